// Round 1
// 162.836 us; speedup vs baseline: 1.0638x; 1.0638x over previous
//
#include <hip/hip_runtime.h>
#include <stdint.h>

#define B_  4
#define NQ_ 2048
#define NP_ 8192
#define D_  256
#define F_  40
#define K_  16

// ---------------- Kernel 1: hash codes -------------------------------------
// Block = 256 threads handles 64 vectors. Stage 64x256 fp32 tile in LDS
// (stride 257 -> 2-way bank access = free), coalesced dword staging loads.
// Wave w computes features [10w, 10w+10) for vector = lane; proj base forced
// scalar via readfirstlane so proj reads become s_load (wave-uniform).
// Accumulation order d=0..255 sequential == round-1 order (signs matched np).
__global__ __launch_bounds__(256) void hash_kernel(
    const float* __restrict__ qp, const float* __restrict__ pp,
    const float* __restrict__ proj, uint64_t* __restrict__ qcodes,
    uint64_t* __restrict__ pcodes) {
  __shared__ float tile[64 * 257];
  int t = threadIdx.x;
  int v0 = blockIdx.x * 64;  // first vector in concat [queries; points] space
  bool isQ = v0 < B_ * NQ_;
  const float* src =
      isQ ? (qp + (size_t)v0 * D_) : (pp + (size_t)(v0 - B_ * NQ_) * D_);

  // Stage: iter i loads row i; thread t covers column t (coalesced dwords).
#pragma unroll 8
  for (int i = 0; i < 64; ++i) tile[i * 257 + t] = src[i * 256 + t];
  __syncthreads();

  int lane = t & 63, w = t >> 6;
  int fbase = __builtin_amdgcn_readfirstlane(w * 10);
  const float* pj = proj + (size_t)fbase * 256;

  float acc[10];
#pragma unroll
  for (int f = 0; f < 10; ++f) acc[f] = 0.0f;
#pragma unroll 4
  for (int d = 0; d < 256; ++d) {
    float x = tile[lane * 257 + d];  // bank (lane+d)%32 -> 2-way, free
#pragma unroll
    for (int f = 0; f < 10; ++f) acc[f] = fmaf(x, pj[f * 256 + d], acc[f]);
  }
  unsigned bits = 0;
#pragma unroll
  for (int f = 0; f < 10; ++f)
    if (acc[f] > 0.0f) bits |= 1u << f;

  // Combine the 4 waves' 10-bit chunks per vector (reuse tile LDS).
  __syncthreads();
  unsigned short* cb = (unsigned short*)tile;
  cb[lane * 4 + w] = (unsigned short)bits;
  __syncthreads();
  if (w == 0) {
    uint64_t code = (uint64_t)cb[lane * 4 + 0] |
                    ((uint64_t)cb[lane * 4 + 1] << 10) |
                    ((uint64_t)cb[lane * 4 + 2] << 20) |
                    ((uint64_t)cb[lane * 4 + 3] << 30);
    int gv = v0 + lane;
    if (isQ) qcodes[gv] = code;
    else pcodes[gv - B_ * NQ_] = code;
  }
}

// ---------------- Kernel 2: exact top-16 by (dist, index) -------------------
// 1024-thread block = 16 query-waves sharing one 64KB code tile ->
// 2 blocks/CU = 32 waves/CU (full occupancy).
// v2: FUSED pass 1 — in a single tile scan, count nb = #{d<8} and build the
// fine 8-bin histogram of the fixed bucket d in [8,16) (where the 16th
// smallest of 8192 ~Binomial(40,1/2) distances lands essentially always:
// E[#{d<=7}]≈0.3, E[#{d<=15}]≈600). This deletes the old pass-2 tile re-scan
// (64 ds_read_b128 + popcount recompute per wave). Exact fallback: if the
// 16th element is NOT in [8,16) for this query (nb>=16 or nb+fine<16), run
// the original coarse+fine LDS passes (wave-uniform cold branch, ~never hit).
__global__ __launch_bounds__(1024) void select_kernel(
    const uint64_t* __restrict__ qcodes, const uint64_t* __restrict__ pcodes,
    float* __restrict__ outIdx, float* __restrict__ outDist) {
  __shared__ ulonglong2 ldsP2[NP_ / 2];  // 64 KB
  __shared__ unsigned keybuf[16][K_];
  uint64_t* ldsP = (uint64_t*)ldsP2;

  int tid = threadIdx.x;
  int bb = blockIdx.x >> 7;  // 128 blocks per batch
  const ulonglong2* pb2 = (const ulonglong2*)(pcodes + (size_t)bb * NP_);
  for (int i = tid; i < NP_ / 2; i += 1024) ldsP2[i] = pb2[i];  // dwordx4
  __syncthreads();

  int w = tid >> 6, lane = tid & 63;
  int qg = blockIdx.x * 16 + w;  // global query id
  uint64_t qc = qcodes[qg];
  const uint64_t M = 0x00FF00FF00FF00FFull;

  // ---- Fused pass 1: nb = #{d<8}; fine 8-bin histogram of d in [8,16) ----
  unsigned nb = 0;
  uint64_t cf = 0;
#pragma unroll 4
  for (int j = 0; j < 64; ++j) {
    ulonglong2 pc = ldsP2[j * 64 + lane];
    unsigned d0 = (unsigned)__popcll(qc ^ pc.x);
    unsigned d1 = (unsigned)__popcll(qc ^ pc.y);
    nb += (d0 < 8u) + (d1 < 8u);
    unsigned r0 = d0 - 8u, r1 = d1 - 8u;  // unsigned wrap for d<8
    uint64_t a0 = (r0 < 8u) ? (1ull << (r0 << 3)) : 0ull;
    uint64_t a1 = (r1 < 8u) ? (1ull << (r1 << 3)) : 0ull;
    cf += a0 + a1;  // per-lane 8-bit fields, counts <=128: no overflow
  }
  uint64_t e = cf & M, o = (cf >> 8) & M;
#pragma unroll
  for (int s = 1; s < 64; s <<= 1) {
    e += __shfl_xor(e, s);
    o += __shfl_xor(o, s);
    nb += __shfl_xor(nb, s);
  }

  int t = 0;
  unsigned n_lt = 0;
  bool ok = false;
  if (nb < (unsigned)K_) {
    unsigned cum = nb;
#pragma unroll
    for (int r = 0; r < 8; ++r) {
      unsigned c = (unsigned)(((r & 1) ? o : e) >> ((r >> 1) * 16)) & 0xFFFFu;
      if (!ok && cum + c >= K_) { t = 8 + r; n_lt = cum; ok = true; }
      cum += c;
    }
  }

  if (!ok) {
    // ---- Exact fallback: original coarse + fine LDS passes (cold) ----
    uint64_t c8 = 0;
#pragma unroll 4
    for (int j = 0; j < 64; ++j) {
      ulonglong2 pc = ldsP2[j * 64 + lane];
      int d0 = __popcll(qc ^ pc.x);
      int d1 = __popcll(qc ^ pc.y);
      c8 += (1ull << (d0 & 56)) + (1ull << (d1 & 56));  // (d>>3)*8 == d&56
    }
    uint64_t e2 = c8 & M, o2 = (c8 >> 8) & M;
#pragma unroll
    for (int s = 1; s < 64; s <<= 1) {
      e2 += __shfl_xor(e2, s);
      o2 += __shfl_xor(o2, s);
    }
    int Bb = 0;
    unsigned nbefore = 0, cum = 0;
    bool found = false;
#pragma unroll
    for (int k2 = 0; k2 < 6; ++k2) {
      unsigned c = (unsigned)(((k2 & 1) ? o2 : e2) >> ((k2 >> 1) * 16)) & 0xFFFFu;
      if (!found && cum + c >= K_) { Bb = k2; nbefore = cum; found = true; }
      cum += c;
    }
    int base = Bb * 8;
    uint64_t cff = 0;
#pragma unroll 4
    for (int j = 0; j < 64; ++j) {
      ulonglong2 pc = ldsP2[j * 64 + lane];
      unsigned r0 = (unsigned)(__popcll(qc ^ pc.x) - base);
      unsigned r1 = (unsigned)(__popcll(qc ^ pc.y) - base);
      if (r0 < 8u) cff += 1ull << (r0 << 3);
      if (r1 < 8u) cff += 1ull << (r1 << 3);
    }
    uint64_t ef = cff & M, of = (cff >> 8) & M;
#pragma unroll
    for (int s = 1; s < 64; s <<= 1) {
      ef += __shfl_xor(ef, s);
      of += __shfl_xor(of, s);
    }
    unsigned cum2 = nbefore;
    bool f2 = false;
#pragma unroll
    for (int r = 0; r < 8; ++r) {
      unsigned c = (unsigned)(((r & 1) ? of : ef) >> ((r >> 1) * 16)) & 0xFFFFu;
      if (!f2 && cum2 + c >= K_) { t = base + r; n_lt = cum2; f2 = true; }
      cum2 += c;
    }
  }
  unsigned r_need = K_ - n_lt;  // dist==t entries to take (lowest index)

  // ---- Pass 3: collect keys in index order; skip empty iterations ----
  unsigned cl = 0, ce = 0;
  uint64_t lmask = (1ull << lane) - 1;
  for (int j = 0; j < 128; ++j) {
    int p = j * 64 + lane;
    int d = __popcll(qc ^ ldsP[p]);
    if (__any(d <= t)) {
      bool blt = (d < t), beq = (d == t);
      uint64_t mlt = __ballot(blt), meq = __ballot(beq);
      if (blt)
        keybuf[w][cl + (unsigned)__popcll(mlt & lmask)] =
            ((unsigned)d << 13) | (unsigned)p;
      if (beq) {
        unsigned pos = ce + (unsigned)__popcll(meq & lmask);
        if (pos < r_need)
          keybuf[w][n_lt + pos] = ((unsigned)d << 13) | (unsigned)p;
      }
      cl += (unsigned)__popcll(mlt);
      ce += (unsigned)__popcll(meq);
    }
  }
  __syncthreads();

  // ---- rank-sort the 16 keys (distinct: idx embedded) and emit ----
  if (lane < K_) {
    unsigned my = keybuf[w][lane];
    int rank = 0;
#pragma unroll
    for (int jj = 0; jj < K_; ++jj) rank += (keybuf[w][jj] < my) ? 1 : 0;
    int off = qg * K_ + rank;
    outIdx[off]  = (float)(my & 8191u);  // index
    outDist[off] = (float)(my >> 13);    // distance
  }
}

extern "C" void kernel_launch(void* const* d_in, const int* in_sizes, int n_in,
                              void* d_out, int out_size, void* d_ws, size_t ws_size,
                              hipStream_t stream) {
  const float* qp   = (const float*)d_in[0];
  const float* pp   = (const float*)d_in[1];
  const float* proj = (const float*)d_in[2];
  // d_in[3] is k (always 16) — hardcoded.

  uint64_t* pcodes = (uint64_t*)d_ws;            // B*NP u64
  uint64_t* qcodes = pcodes + (size_t)B_ * NP_;  // B*NQ u64

  float* outIdx  = (float*)d_out;                   // B*NQ*K indices (as float)
  float* outDist = outIdx + (size_t)B_ * NQ_ * K_;  // B*NQ*K distances

  int total_vecs = B_ * (NQ_ + NP_);  // 40960
  hash_kernel<<<total_vecs / 64, 256, 0, stream>>>(qp, pp, proj, qcodes, pcodes);
  select_kernel<<<B_ * NQ_ / 16, 1024, 0, stream>>>(qcodes, pcodes, outIdx, outDist);
}